// Round 1
// baseline (568.863 us; speedup 1.0000x reference)
//
#include <hip/hip_runtime.h>
#include <hip/hip_bf16.h>

typedef __hip_bfloat16 bf16;
typedef __attribute__((ext_vector_type(8))) __bf16 bf16x8;
typedef __attribute__((ext_vector_type(4))) float f32x4;

#define SEQ 2048
#define HID 4096
#define NH 32
#define NKV 8
#define HD 128
#define KVDIM 1024

__device__ __forceinline__ void gl_lds16(const void* g, void* lds) {
  __builtin_amdgcn_global_load_lds((const __attribute__((address_space(1))) void*)g,
                                   (__attribute__((address_space(3))) void*)lds,
                                   16, 0, 0);
}

// ---------------- elementwise fp32 -> bf16 ----------------
__global__ void cvt_kernel(const float* __restrict__ in, bf16* __restrict__ out, int n) {
  int i = (blockIdx.x * blockDim.x + threadIdx.x) * 4;
  if (i >= n) return;
  float4 v = *reinterpret_cast<const float4*>(in + i);
  bf16 o[4] = {__float2bfloat16(v.x), __float2bfloat16(v.y),
               __float2bfloat16(v.z), __float2bfloat16(v.w)};
  *reinterpret_cast<short4*>(out + i) = *reinterpret_cast<const short4*>(o);
}

// ---------------- tiled transpose fp32[R][C] -> bf16[C][R] ----------------
__global__ void transpose_cvt_kernel(const float* __restrict__ in, bf16* __restrict__ out,
                                     int R, int C) {
  __shared__ float tile[32][33];
  int c0 = blockIdx.x * 32, r0 = blockIdx.y * 32;
  int tx = threadIdx.x, ty = threadIdx.y;
#pragma unroll
  for (int i = 0; i < 32; i += 8)
    tile[ty + i][tx] = in[(size_t)(r0 + ty + i) * C + (c0 + tx)];
  __syncthreads();
#pragma unroll
  for (int i = 0; i < 32; i += 8)
    out[(size_t)(c0 + ty + i) * R + (r0 + tx)] = __float2bfloat16(tile[tx][ty + i]);
}

// ---------------- RoPE fp32 -> bf16 (pos = row index) ----------------
__global__ void rope_cvt_kernel(const float* __restrict__ in, bf16* __restrict__ out,
                                int nheads, int hshift) {
  int idx = blockIdx.x * blockDim.x + threadIdx.x;  // over SEQ*nheads*64
  int i = idx & 63;
  int h = (idx >> 6) & (nheads - 1);
  int s = idx >> (6 + hshift);
  if (s >= SEQ) return;
  float inv = __expf(-(float)i * 0.14391156831212787f);  // ln(10000)/64
  float ang = (float)s * inv;
  float sn, cs;
  __sincosf(ang, &sn, &cs);
  size_t base = (size_t)s * ((size_t)nheads * HD) + (size_t)h * HD + i;
  float x1 = in[base], x2 = in[base + 64];
  out[base]      = __float2bfloat16(x1 * cs - x2 * sn);
  out[base + 64] = __float2bfloat16(x2 * cs + x1 * sn);
}

// ---------------- GEMM: C[M][N] = A[M][K] * Bt[N][K]^T + bias ----------------
// BM=BN=128, BK=64, 256 threads (4 waves, 2x2), 16x16x32 bf16 MFMA.
__global__ __launch_bounds__(256) void gemm_bt_kernel(
    const bf16* __restrict__ A, const bf16* __restrict__ Bt,
    const float* __restrict__ bias, float* __restrict__ C,
    int M, int N, int K) {
  __shared__ bf16 As[128 * 64];
  __shared__ bf16 Bs[128 * 64];
  const int tid = threadIdx.x;
  const int lane = tid & 63;
  const int w = tid >> 6;
  const int wm = w >> 1, wn = w & 1;
  const int m0 = blockIdx.y * 128;
  const int n0 = blockIdx.x * 128;

  f32x4 acc[4][4];
  const f32x4 z = {0.f, 0.f, 0.f, 0.f};
#pragma unroll
  for (int i = 0; i < 4; i++)
#pragma unroll
    for (int j = 0; j < 4; j++) acc[i][j] = z;

  for (int kk = 0; kk < K; kk += 64) {
    // stage A,B (row-major [128][64] bf16, XOR-swizzled via pre-swizzled source)
#pragma unroll
    for (int it = 0; it < 4; ++it) {
      int c = w * 4 + it;
      int row = c * 8 + (lane >> 3);
      int sb = ((lane & 7) * 16) ^ ((row & 7) << 4);
      gl_lds16(A + (size_t)(m0 + row) * K + kk + (sb >> 1), &As[c * 512]);
      gl_lds16(Bt + (size_t)(n0 + row) * K + kk + (sb >> 1), &Bs[c * 512]);
    }
    __syncthreads();
#pragma unroll
    for (int ks = 0; ks < 64; ks += 32) {
      bf16x8 a[4], b[4];
#pragma unroll
      for (int mi = 0; mi < 4; ++mi) {
        int r = wm * 64 + mi * 16 + (lane & 15);
        int byt = r * 128 + (((ks + (lane >> 4) * 8) * 2) ^ ((r & 7) << 4));
        a[mi] = *reinterpret_cast<const bf16x8*>(reinterpret_cast<const char*>(As) + byt);
      }
#pragma unroll
      for (int ni = 0; ni < 4; ++ni) {
        int r = wn * 64 + ni * 16 + (lane & 15);
        int byt = r * 128 + (((ks + (lane >> 4) * 8) * 2) ^ ((r & 7) << 4));
        b[ni] = *reinterpret_cast<const bf16x8*>(reinterpret_cast<const char*>(Bs) + byt);
      }
#pragma unroll
      for (int mi = 0; mi < 4; ++mi)
#pragma unroll
        for (int ni = 0; ni < 4; ++ni)
          acc[mi][ni] = __builtin_amdgcn_mfma_f32_16x16x32_bf16(a[mi], b[ni], acc[mi][ni], 0, 0, 0);
    }
    __syncthreads();
  }
#pragma unroll
  for (int ni = 0; ni < 4; ++ni) {
    int col = n0 + wn * 64 + ni * 16 + (lane & 15);
    float bv = bias ? bias[col] : 0.0f;
#pragma unroll
    for (int mi = 0; mi < 4; ++mi) {
      int rbase = m0 + wm * 64 + mi * 16 + (lane >> 4) * 4;
#pragma unroll
      for (int r = 0; r < 4; ++r)
        C[(size_t)(rbase + r) * N + col] = acc[mi][ni][r] + bv;
    }
  }
}

// ---------------- flash attention ----------------
// grid (SEQ/64, NH); 4 waves, each owns 16 q-rows; KV tiles of 64.
__global__ __launch_bounds__(256) void attn_kernel(
    const bf16* __restrict__ Q,   // [SEQ][HID]
    const bf16* __restrict__ Kb,  // [SEQ][KVDIM]
    const bf16* __restrict__ Vt,  // [KVDIM][SEQ]  (row = kvh*128+d)
    bf16* __restrict__ AO) {      // [SEQ][HID]
  __shared__ bf16 Ks[64 * 128];   // [kv][d], swizzled
  __shared__ bf16 Vs[128 * 64];   // [d][kv], swizzled
  __shared__ bf16 Ps[4][16 * 64]; // per-wave [q][kv], swizzled
  const int tid = threadIdx.x, lane = tid & 63, w = tid >> 6;
  const int qb = blockIdx.x;
  const int H = blockIdx.y;
  const int kvh = H >> 2;
  const int qbase = qb * 64;
  const int qw = qbase + w * 16;

  bf16x8 aq[4];
#pragma unroll
  for (int kd = 0; kd < 4; ++kd) {
    int row = qw + (lane & 15);
    int d = kd * 32 + (lane >> 4) * 8;
    aq[kd] = *reinterpret_cast<const bf16x8*>(Q + (size_t)row * HID + H * HD + d);
  }

  float m_run[4], l_run[4];
  f32x4 o[8];
  const f32x4 z = {0.f, 0.f, 0.f, 0.f};
#pragma unroll
  for (int r = 0; r < 4; ++r) { m_run[r] = -1e30f; l_run[r] = 0.0f; }
#pragma unroll
  for (int dt = 0; dt < 8; ++dt) o[dt] = z;

  const float scale = 0.08838834764831845f;  // 1/sqrt(128)

  for (int t = 0; t <= qb; ++t) {
    int kvbase = t * 64;
    // stage K tile: 64 rows x 256B
#pragma unroll
    for (int it = 0; it < 4; ++it) {
      int c = w * 4 + it;
      int row = c * 4 + (lane >> 4);
      int sb = ((lane & 15) * 16) ^ ((row & 7) << 4);
      gl_lds16(Kb + (size_t)(kvbase + row) * KVDIM + kvh * HD + (sb >> 1), &Ks[c * 512]);
    }
    // stage V tile: 128 rows x 128B
#pragma unroll
    for (int it = 0; it < 4; ++it) {
      int c = w * 4 + it;
      int row = c * 8 + (lane >> 3);
      int sb = ((lane & 7) * 16) ^ ((row & 7) << 4);
      gl_lds16(Vt + (size_t)(kvh * HD + row) * SEQ + kvbase + (sb >> 1), &Vs[c * 512]);
    }
    __syncthreads();

    // S = Q K^T  (4 kv-subtiles of 16)
    f32x4 sf[4];
#pragma unroll
    for (int j = 0; j < 4; ++j) sf[j] = z;
#pragma unroll
    for (int j = 0; j < 4; ++j) {
#pragma unroll
      for (int kd = 0; kd < 4; ++kd) {
        int r = j * 16 + (lane & 15);
        int byt = r * 256 + (((kd * 32 + (lane >> 4) * 8) * 2) ^ ((r & 7) << 4));
        bf16x8 b = *reinterpret_cast<const bf16x8*>(reinterpret_cast<const char*>(Ks) + byt);
        sf[j] = __builtin_amdgcn_mfma_f32_16x16x32_bf16(aq[kd], b, sf[j], 0, 0, 0);
      }
    }

    float vals[4][4];
    bool diag = (t == qb);
#pragma unroll
    for (int j = 0; j < 4; ++j)
#pragma unroll
      for (int r = 0; r < 4; ++r) {
        float v = sf[j][r] * scale;
        if (diag) {
          int qa = qw + (lane >> 4) * 4 + r;
          int ka = kvbase + j * 16 + (lane & 15);
          if (ka > qa) v = -1e30f;
        }
        vals[j][r] = v;
      }

    float mt[4], alpha[4];
#pragma unroll
    for (int r = 0; r < 4; ++r) {
      float m = fmaxf(fmaxf(vals[0][r], vals[1][r]), fmaxf(vals[2][r], vals[3][r]));
#pragma unroll
      for (int sh = 8; sh >= 1; sh >>= 1) m = fmaxf(m, __shfl_xor(m, sh, 16));
      float mn = fmaxf(m_run[r], m);
      alpha[r] = __expf(m_run[r] - mn);
      m_run[r] = mn;
      mt[r] = mn;
    }

    float rs[4] = {0.f, 0.f, 0.f, 0.f};
#pragma unroll
    for (int j = 0; j < 4; ++j)
#pragma unroll
      for (int r = 0; r < 4; ++r) {
        float p = __expf(vals[j][r] - mt[r]);
        rs[r] += p;
        int prow = (lane >> 4) * 4 + r;
        int pcol = j * 16 + (lane & 15);
        int byt = prow * 128 + ((pcol * 2) ^ ((prow & 7) << 4));
        *reinterpret_cast<bf16*>(reinterpret_cast<char*>(&Ps[w][0]) + byt) = __float2bfloat16(p);
      }
#pragma unroll
    for (int r = 0; r < 4; ++r) {
#pragma unroll
      for (int sh = 8; sh >= 1; sh >>= 1) rs[r] += __shfl_xor(rs[r], sh, 16);
      l_run[r] = l_run[r] * alpha[r] + rs[r];
    }
#pragma unroll
    for (int dt = 0; dt < 8; ++dt)
#pragma unroll
      for (int r = 0; r < 4; ++r) o[dt][r] *= alpha[r];

    // O += P V
    bf16x8 pa[2];
#pragma unroll
    for (int ks = 0; ks < 2; ++ks) {
      int prow = lane & 15;
      int byt = prow * 128 + (((ks * 32 + (lane >> 4) * 8) * 2) ^ ((prow & 7) << 4));
      pa[ks] = *reinterpret_cast<const bf16x8*>(reinterpret_cast<const char*>(&Ps[w][0]) + byt);
    }
#pragma unroll
    for (int dt = 0; dt < 8; ++dt)
#pragma unroll
      for (int ks = 0; ks < 2; ++ks) {
        int vrow = dt * 16 + (lane & 15);
        int byt = vrow * 128 + (((ks * 32 + (lane >> 4) * 8) * 2) ^ ((vrow & 7) << 4));
        bf16x8 vb = *reinterpret_cast<const bf16x8*>(reinterpret_cast<const char*>(Vs) + byt);
        o[dt] = __builtin_amdgcn_mfma_f32_16x16x32_bf16(pa[ks], vb, o[dt], 0, 0, 0);
      }
    __syncthreads();
  }

#pragma unroll
  for (int dt = 0; dt < 8; ++dt)
#pragma unroll
    for (int r = 0; r < 4; ++r) {
      int qa = qw + (lane >> 4) * 4 + r;
      int d = dt * 16 + (lane & 15);
      AO[(size_t)qa * HID + H * HD + d] = __float2bfloat16(o[dt][r] / l_run[r]);
    }
}

extern "C" void kernel_launch(void* const* d_in, const int* in_sizes, int n_in,
                              void* d_out, int out_size, void* d_ws, size_t ws_size,
                              hipStream_t stream) {
  const float* hidden = (const float*)d_in[0];
  const float* Wq = (const float*)d_in[2];
  const float* bq = (const float*)d_in[3];
  const float* Wk = (const float*)d_in[4];
  const float* bk = (const float*)d_in[5];
  const float* Wv = (const float*)d_in[6];
  const float* bv = (const float*)d_in[7];
  const float* Wo = (const float*)d_in[8];
  float* out = (float*)d_out;

  char* w = (char*)d_ws;
  bf16* Xb  = (bf16*)w; w += (size_t)SEQ * HID * 2;
  bf16* Wqt = (bf16*)w; w += (size_t)HID * HID * 2;
  bf16* Wkt = (bf16*)w; w += (size_t)KVDIM * HID * 2;
  bf16* Wvt = (bf16*)w; w += (size_t)KVDIM * HID * 2;
  bf16* Wot = (bf16*)w; w += (size_t)HID * HID * 2;
  bf16* Qb  = (bf16*)w; w += (size_t)SEQ * HID * 2;
  bf16* Kb  = (bf16*)w; w += (size_t)SEQ * KVDIM * 2;
  bf16* Vt  = (bf16*)w; w += (size_t)KVDIM * SEQ * 2;
  float* Qf = (float*)w; w += (size_t)SEQ * HID * 4;
  float* Kf = (float*)w; w += (size_t)SEQ * KVDIM * 4;
  float* Vf = (float*)w; w += (size_t)SEQ * KVDIM * 4;
  bf16* AO = (bf16*)Qf;  // alias: Qf dead after RoPE

  cvt_kernel<<<(SEQ * HID) / 1024, 256, 0, stream>>>(hidden, Xb, SEQ * HID);
  transpose_cvt_kernel<<<dim3(HID / 32, HID / 32), dim3(32, 8), 0, stream>>>(Wq, Wqt, HID, HID);
  transpose_cvt_kernel<<<dim3(KVDIM / 32, HID / 32), dim3(32, 8), 0, stream>>>(Wk, Wkt, HID, KVDIM);
  transpose_cvt_kernel<<<dim3(KVDIM / 32, HID / 32), dim3(32, 8), 0, stream>>>(Wv, Wvt, HID, KVDIM);
  transpose_cvt_kernel<<<dim3(HID / 32, HID / 32), dim3(32, 8), 0, stream>>>(Wo, Wot, HID, HID);

  gemm_bt_kernel<<<dim3(HID / 128, SEQ / 128), 256, 0, stream>>>(Xb, Wqt, bq, Qf, SEQ, HID, HID);
  gemm_bt_kernel<<<dim3(KVDIM / 128, SEQ / 128), 256, 0, stream>>>(Xb, Wkt, bk, Kf, SEQ, KVDIM, HID);
  gemm_bt_kernel<<<dim3(KVDIM / 128, SEQ / 128), 256, 0, stream>>>(Xb, Wvt, bv, Vf, SEQ, KVDIM, HID);

  rope_cvt_kernel<<<(SEQ * NH * 64) / 256, 256, 0, stream>>>(Qf, Qb, NH, 5);
  rope_cvt_kernel<<<(SEQ * NKV * 64) / 256, 256, 0, stream>>>(Kf, Kb, NKV, 3);
  transpose_cvt_kernel<<<dim3(KVDIM / 32, SEQ / 32), dim3(32, 8), 0, stream>>>(Vf, Vt, SEQ, KVDIM);

  attn_kernel<<<dim3(SEQ / 64, NH), 256, 0, stream>>>(Qb, Kb, Vt, AO);

  gemm_bt_kernel<<<dim3(HID / 128, SEQ / 128), 256, 0, stream>>>(AO, Wot, nullptr, out, SEQ, HID, HID);
}

// Round 2
// 410.485 us; speedup vs baseline: 1.3858x; 1.3858x over previous
//
#include <hip/hip_runtime.h>
#include <hip/hip_bf16.h>

typedef __hip_bfloat16 bf16;
typedef __attribute__((ext_vector_type(8))) __bf16 bf16x8;
typedef __attribute__((ext_vector_type(4))) float f32x4;

#define SEQ 2048
#define HID 4096
#define NH 32
#define NKV 8
#define HD 128
#define KVDIM 1024
#define QKVN 6144

__device__ __forceinline__ void gl_lds16(const void* g, void* lds) {
  __builtin_amdgcn_global_load_lds((const __attribute__((address_space(1))) void*)g,
                                   (__attribute__((address_space(3))) void*)lds,
                                   16, 0, 0);
}

// ---------------- elementwise fp32 -> bf16 ----------------
__global__ void cvt_kernel(const float* __restrict__ in, bf16* __restrict__ out, int n) {
  int i = (blockIdx.x * blockDim.x + threadIdx.x) * 4;
  if (i >= n) return;
  float4 v = *reinterpret_cast<const float4*>(in + i);
  bf16 o[4] = {__float2bfloat16(v.x), __float2bfloat16(v.y),
               __float2bfloat16(v.z), __float2bfloat16(v.w)};
  *reinterpret_cast<short4*>(out + i) = *reinterpret_cast<const short4*>(o);
}

// ---------------- bias concat [4096|1024|1024] ----------------
__global__ void concat_bias_kernel(const float* __restrict__ bq, const float* __restrict__ bk,
                                   const float* __restrict__ bv, float* __restrict__ o) {
  int i = blockIdx.x * blockDim.x + threadIdx.x;
  if (i >= QKVN) return;
  o[i] = (i < HID) ? bq[i] : (i < HID + KVDIM ? bk[i - HID] : bv[i - HID - KVDIM]);
}

// ---------------- tiled transpose fp32[R][C](stride si) -> bf16[C][R](stride so) ----------------
__global__ void transpose_cvt_kernel(const float* __restrict__ in, bf16* __restrict__ out,
                                     int si, int so) {
  __shared__ float tile[32][33];
  int c0 = blockIdx.x * 32, r0 = blockIdx.y * 32;
  int tx = threadIdx.x, ty = threadIdx.y;
#pragma unroll
  for (int i = 0; i < 32; i += 8)
    tile[ty + i][tx] = in[(size_t)(r0 + ty + i) * si + (c0 + tx)];
  __syncthreads();
#pragma unroll
  for (int i = 0; i < 32; i += 8)
    out[(size_t)(c0 + ty + i) * so + (r0 + tx)] = __float2bfloat16(tile[tx][ty + i]);
}

// ---------------- RoPE fp32(stride si) -> bf16 (pos = row index) ----------------
__global__ void rope_cvt_kernel(const float* __restrict__ in, bf16* __restrict__ out,
                                int nheads, int hshift, int si) {
  int idx = blockIdx.x * blockDim.x + threadIdx.x;  // over SEQ*nheads*64
  int i = idx & 63;
  int h = (idx >> 6) & (nheads - 1);
  int s = idx >> (6 + hshift);
  if (s >= SEQ) return;
  float inv = __expf(-(float)i * 0.14391156831212787f);  // ln(10000)/64
  float ang = (float)s * inv;
  float sn, cs;
  __sincosf(ang, &sn, &cs);
  size_t bi = (size_t)s * si + (size_t)h * HD + i;
  size_t bo = (size_t)s * ((size_t)nheads * HD) + (size_t)h * HD + i;
  float x1 = in[bi], x2 = in[bi + 64];
  out[bo]      = __float2bfloat16(x1 * cs - x2 * sn);
  out[bo + 64] = __float2bfloat16(x2 * cs + x1 * sn);
}

// ---------------- GEMM: C[M][N] = A[M][K] * Bt[N][K]^T + bias ----------------
// BM=BN=128, BK=64, 256 threads (4 waves, 2x2), 16x16x32 bf16 MFMA.
__global__ __launch_bounds__(256) void gemm_bt_kernel(
    const bf16* __restrict__ A, const bf16* __restrict__ Bt,
    const float* __restrict__ bias, float* __restrict__ C,
    int M, int N, int K) {
  __shared__ bf16 As[128 * 64];
  __shared__ bf16 Bs[128 * 64];
  const int tid = threadIdx.x;
  const int lane = tid & 63;
  const int w = tid >> 6;
  const int wm = w >> 1, wn = w & 1;
  const int m0 = blockIdx.y * 128;
  const int n0 = blockIdx.x * 128;

  f32x4 acc[4][4];
  const f32x4 z = {0.f, 0.f, 0.f, 0.f};
#pragma unroll
  for (int i = 0; i < 4; i++)
#pragma unroll
    for (int j = 0; j < 4; j++) acc[i][j] = z;

  for (int kk = 0; kk < K; kk += 64) {
#pragma unroll
    for (int it = 0; it < 4; ++it) {
      int c = w * 4 + it;
      int row = c * 8 + (lane >> 3);
      int sb = ((lane & 7) * 16) ^ ((row & 7) << 4);
      gl_lds16(A + (size_t)(m0 + row) * K + kk + (sb >> 1), &As[c * 512]);
      gl_lds16(Bt + (size_t)(n0 + row) * K + kk + (sb >> 1), &Bs[c * 512]);
    }
    __syncthreads();
#pragma unroll
    for (int ks = 0; ks < 64; ks += 32) {
      bf16x8 a[4], b[4];
#pragma unroll
      for (int mi = 0; mi < 4; ++mi) {
        int r = wm * 64 + mi * 16 + (lane & 15);
        int byt = r * 128 + (((ks + (lane >> 4) * 8) * 2) ^ ((r & 7) << 4));
        a[mi] = *reinterpret_cast<const bf16x8*>(reinterpret_cast<const char*>(As) + byt);
      }
#pragma unroll
      for (int ni = 0; ni < 4; ++ni) {
        int r = wn * 64 + ni * 16 + (lane & 15);
        int byt = r * 128 + (((ks + (lane >> 4) * 8) * 2) ^ ((r & 7) << 4));
        b[ni] = *reinterpret_cast<const bf16x8*>(reinterpret_cast<const char*>(Bs) + byt);
      }
#pragma unroll
      for (int mi = 0; mi < 4; ++mi)
#pragma unroll
        for (int ni = 0; ni < 4; ++ni)
          acc[mi][ni] = __builtin_amdgcn_mfma_f32_16x16x32_bf16(a[mi], b[ni], acc[mi][ni], 0, 0, 0);
    }
    __syncthreads();
  }
#pragma unroll
  for (int ni = 0; ni < 4; ++ni) {
    int col = n0 + wn * 64 + ni * 16 + (lane & 15);
    float bv = bias ? bias[col] : 0.0f;
#pragma unroll
    for (int mi = 0; mi < 4; ++mi) {
      int rbase = m0 + wm * 64 + mi * 16 + (lane >> 4) * 4;
#pragma unroll
      for (int r = 0; r < 4; ++r)
        C[(size_t)(rbase + r) * N + col] = acc[mi][ni][r] + bv;
    }
  }
}

// ---------------- flash attention ----------------
// 1-D grid of 1024 blocks; H = b&31 (minor: adjacent blocks share KV head -> L2),
// qb drawn from {g,15-g,16+g,31-g} so any CU's blocks at +256 stride get equal work.
__global__ __launch_bounds__(256) void attn_kernel(
    const bf16* __restrict__ Q,   // [SEQ][HID]
    const bf16* __restrict__ Kb,  // [SEQ][KVDIM]
    const bf16* __restrict__ Vt,  // [KVDIM][SEQ]  (row = kvh*128+d)
    bf16* __restrict__ AO) {      // [SEQ][HID]
  __shared__ bf16 Ks[64 * 128];   // [kv][d], swizzled
  __shared__ bf16 Vs[128 * 64];   // [d][kv], swizzled
  __shared__ bf16 Ps[4][16 * 64]; // per-wave [q][kv], swizzled
  const int tid = threadIdx.x, lane = tid & 63, w = tid >> 6;
  const int b = blockIdx.x;
  const int H = b & 31;
  const int j0 = b >> 5;
  const int g = j0 & 7, t0 = j0 >> 3;
  const int qb = (t0 == 0) ? g : (t0 == 1) ? 15 - g : (t0 == 2) ? 16 + g : 31 - g;
  const int kvh = H >> 2;
  const int qw = qb * 64 + w * 16;

  bf16x8 aq[4];
#pragma unroll
  for (int kd = 0; kd < 4; ++kd) {
    int row = qw + (lane & 15);
    int d = kd * 32 + (lane >> 4) * 8;
    aq[kd] = *reinterpret_cast<const bf16x8*>(Q + (size_t)row * HID + H * HD + d);
  }

  float m_run[4], l_run[4];
  f32x4 o[8];
  const f32x4 z = {0.f, 0.f, 0.f, 0.f};
#pragma unroll
  for (int r = 0; r < 4; ++r) { m_run[r] = -1e30f; l_run[r] = 0.0f; }
#pragma unroll
  for (int dt = 0; dt < 8; ++dt) o[dt] = z;

  const float scale = 0.08838834764831845f;  // 1/sqrt(128)

  for (int t = 0; t <= qb; ++t) {
    int kvbase = t * 64;
#pragma unroll
    for (int it = 0; it < 4; ++it) {
      int c = w * 4 + it;
      int row = c * 4 + (lane >> 4);
      int sb = ((lane & 15) * 16) ^ ((row & 7) << 4);
      gl_lds16(Kb + (size_t)(kvbase + row) * KVDIM + kvh * HD + (sb >> 1), &Ks[c * 512]);
    }
#pragma unroll
    for (int it = 0; it < 4; ++it) {
      int c = w * 4 + it;
      int row = c * 8 + (lane >> 3);
      int sb = ((lane & 7) * 16) ^ ((row & 7) << 4);
      gl_lds16(Vt + (size_t)(kvh * HD + row) * SEQ + kvbase + (sb >> 1), &Vs[c * 512]);
    }
    __syncthreads();

    f32x4 sf[4];
#pragma unroll
    for (int j = 0; j < 4; ++j) sf[j] = z;
#pragma unroll
    for (int j = 0; j < 4; ++j) {
#pragma unroll
      for (int kd = 0; kd < 4; ++kd) {
        int r = j * 16 + (lane & 15);
        int byt = r * 256 + (((kd * 32 + (lane >> 4) * 8) * 2) ^ ((r & 7) << 4));
        bf16x8 bfr = *reinterpret_cast<const bf16x8*>(reinterpret_cast<const char*>(Ks) + byt);
        sf[j] = __builtin_amdgcn_mfma_f32_16x16x32_bf16(aq[kd], bfr, sf[j], 0, 0, 0);
      }
    }

    float vals[4][4];
    bool diag = (t == qb);
#pragma unroll
    for (int j = 0; j < 4; ++j)
#pragma unroll
      for (int r = 0; r < 4; ++r) {
        float v = sf[j][r] * scale;
        if (diag) {
          int qa = qw + (lane >> 4) * 4 + r;
          int ka = kvbase + j * 16 + (lane & 15);
          if (ka > qa) v = -1e30f;
        }
        vals[j][r] = v;
      }

    float mt[4], alpha[4];
#pragma unroll
    for (int r = 0; r < 4; ++r) {
      float m = fmaxf(fmaxf(vals[0][r], vals[1][r]), fmaxf(vals[2][r], vals[3][r]));
#pragma unroll
      for (int sh = 8; sh >= 1; sh >>= 1) m = fmaxf(m, __shfl_xor(m, sh, 16));
      float mn = fmaxf(m_run[r], m);
      alpha[r] = __expf(m_run[r] - mn);
      m_run[r] = mn;
      mt[r] = mn;
    }

    float rs[4] = {0.f, 0.f, 0.f, 0.f};
#pragma unroll
    for (int j = 0; j < 4; ++j)
#pragma unroll
      for (int r = 0; r < 4; ++r) {
        float p = __expf(vals[j][r] - mt[r]);
        rs[r] += p;
        int prow = (lane >> 4) * 4 + r;
        int pcol = j * 16 + (lane & 15);
        int byt = prow * 128 + ((pcol * 2) ^ ((prow & 7) << 4));
        *reinterpret_cast<bf16*>(reinterpret_cast<char*>(&Ps[w][0]) + byt) = __float2bfloat16(p);
      }
#pragma unroll
    for (int r = 0; r < 4; ++r) {
#pragma unroll
      for (int sh = 8; sh >= 1; sh >>= 1) rs[r] += __shfl_xor(rs[r], sh, 16);
      l_run[r] = l_run[r] * alpha[r] + rs[r];
    }
#pragma unroll
    for (int dt = 0; dt < 8; ++dt)
#pragma unroll
      for (int r = 0; r < 4; ++r) o[dt][r] *= alpha[r];

    bf16x8 pa[2];
#pragma unroll
    for (int ks = 0; ks < 2; ++ks) {
      int prow = lane & 15;
      int byt = prow * 128 + (((ks * 32 + (lane >> 4) * 8) * 2) ^ ((prow & 7) << 4));
      pa[ks] = *reinterpret_cast<const bf16x8*>(reinterpret_cast<const char*>(&Ps[w][0]) + byt);
    }
#pragma unroll
    for (int dt = 0; dt < 8; ++dt)
#pragma unroll
      for (int ks = 0; ks < 2; ++ks) {
        int vrow = dt * 16 + (lane & 15);
        int byt = vrow * 128 + (((ks * 32 + (lane >> 4) * 8) * 2) ^ ((vrow & 7) << 4));
        bf16x8 vb = *reinterpret_cast<const bf16x8*>(reinterpret_cast<const char*>(Vs) + byt);
        o[dt] = __builtin_amdgcn_mfma_f32_16x16x32_bf16(pa[ks], vb, o[dt], 0, 0, 0);
      }
    __syncthreads();
  }

#pragma unroll
  for (int dt = 0; dt < 8; ++dt)
#pragma unroll
    for (int r = 0; r < 4; ++r) {
      int qa = qw + (lane >> 4) * 4 + r;
      int d = dt * 16 + (lane & 15);
      AO[(size_t)qa * HID + H * HD + d] = __float2bfloat16(o[dt][r] / l_run[r]);
    }
}

extern "C" void kernel_launch(void* const* d_in, const int* in_sizes, int n_in,
                              void* d_out, int out_size, void* d_ws, size_t ws_size,
                              hipStream_t stream) {
  const float* hidden = (const float*)d_in[0];
  const float* Wq = (const float*)d_in[2];
  const float* bq = (const float*)d_in[3];
  const float* Wk = (const float*)d_in[4];
  const float* bk = (const float*)d_in[5];
  const float* Wv = (const float*)d_in[6];
  const float* bv = (const float*)d_in[7];
  const float* Wo = (const float*)d_in[8];
  float* out = (float*)d_out;

  char* w = (char*)d_ws;
  bf16* Xb    = (bf16*)w; w += (size_t)SEQ * HID * 2;
  bf16* Wqkvt = (bf16*)w; w += (size_t)QKVN * HID * 2;   // rows: [Q 4096 | K 1024 | V 1024]
  bf16* Wot   = (bf16*)w; w += (size_t)HID * HID * 2;
  bf16* Qb    = (bf16*)w; w += (size_t)SEQ * HID * 2;
  bf16* Kb    = (bf16*)w; w += (size_t)SEQ * KVDIM * 2;
  bf16* Vt    = (bf16*)w; w += (size_t)KVDIM * SEQ * 2;
  float* bqkv = (float*)w; w += (size_t)QKVN * 4;
  float* Cqkv = (float*)w; w += (size_t)SEQ * QKVN * 4;  // [2048][6144] fused QKV out
  bf16* AO = (bf16*)Cqkv;  // alias: Cqkv dead after rope/V-transpose

  cvt_kernel<<<(SEQ * HID) / 1024, 256, 0, stream>>>(hidden, Xb, SEQ * HID);
  concat_bias_kernel<<<QKVN / 256, 256, 0, stream>>>(bq, bk, bv, bqkv);
  transpose_cvt_kernel<<<dim3(HID / 32, HID / 32), dim3(32, 8), 0, stream>>>(
      Wq, Wqkvt, HID, HID);
  transpose_cvt_kernel<<<dim3(KVDIM / 32, HID / 32), dim3(32, 8), 0, stream>>>(
      Wk, Wqkvt + (size_t)HID * HID, KVDIM, HID);
  transpose_cvt_kernel<<<dim3(KVDIM / 32, HID / 32), dim3(32, 8), 0, stream>>>(
      Wv, Wqkvt + (size_t)(HID + KVDIM) * HID, KVDIM, HID);
  transpose_cvt_kernel<<<dim3(HID / 32, HID / 32), dim3(32, 8), 0, stream>>>(
      Wo, Wot, HID, HID);

  gemm_bt_kernel<<<dim3(QKVN / 128, SEQ / 128), 256, 0, stream>>>(
      Xb, Wqkvt, bqkv, Cqkv, SEQ, QKVN, HID);

  rope_cvt_kernel<<<(SEQ * NH * 64) / 256, 256, 0, stream>>>(Cqkv, Qb, NH, 5, QKVN);
  rope_cvt_kernel<<<(SEQ * NKV * 64) / 256, 256, 0, stream>>>(Cqkv + HID, Kb, NKV, 3, QKVN);
  transpose_cvt_kernel<<<dim3(KVDIM / 32, SEQ / 32), dim3(32, 8), 0, stream>>>(
      Cqkv + HID + KVDIM, Vt, QKVN, SEQ);

  attn_kernel<<<1024, 256, 0, stream>>>(Qb, Kb, Vt, AO);

  gemm_bt_kernel<<<dim3(HID / 128, SEQ / 128), 256, 0, stream>>>(
      AO, Wot, nullptr, out, SEQ, HID, HID);
}

// Round 4
// 403.913 us; speedup vs baseline: 1.4084x; 1.0163x over previous
//
#include <hip/hip_runtime.h>
#include <hip/hip_bf16.h>

typedef __hip_bfloat16 bf16;
typedef __attribute__((ext_vector_type(8))) __bf16 bf16x8;
typedef __attribute__((ext_vector_type(4))) float f32x4;

#define SEQ 2048
#define HID 4096
#define NH 32
#define NKV 8
#define HD 128
#define KVDIM 1024
#define QKVN 6144

__device__ __forceinline__ void gl_lds16(const void* g, void* lds) {
  __builtin_amdgcn_global_load_lds((const __attribute__((address_space(1))) void*)g,
                                   (__attribute__((address_space(3))) void*)lds,
                                   16, 0, 0);
}

// ---------------- elementwise fp32 -> bf16 ----------------
__global__ void cvt_kernel(const float* __restrict__ in, bf16* __restrict__ out, int n) {
  int i = (blockIdx.x * blockDim.x + threadIdx.x) * 4;
  if (i >= n) return;
  float4 v = *reinterpret_cast<const float4*>(in + i);
  bf16 o[4] = {__float2bfloat16(v.x), __float2bfloat16(v.y),
               __float2bfloat16(v.z), __float2bfloat16(v.w)};
  *reinterpret_cast<short4*>(out + i) = *reinterpret_cast<const short4*>(o);
}

// ---------------- bias concat [4096|1024|1024] ----------------
__global__ void concat_bias_kernel(const float* __restrict__ bq, const float* __restrict__ bk,
                                   const float* __restrict__ bv, float* __restrict__ o) {
  int i = blockIdx.x * blockDim.x + threadIdx.x;
  if (i >= QKVN) return;
  o[i] = (i < HID) ? bq[i] : (i < HID + KVDIM ? bk[i - HID] : bv[i - HID - KVDIM]);
}

// ---------------- tiled transpose fp32[R][C](stride si) -> bf16[C][R](stride so) ----------------
__global__ void transpose_cvt_kernel(const float* __restrict__ in, bf16* __restrict__ out,
                                     int si, int so) {
  __shared__ float tile[32][33];
  int c0 = blockIdx.x * 32, r0 = blockIdx.y * 32;
  int tx = threadIdx.x, ty = threadIdx.y;
#pragma unroll
  for (int i = 0; i < 32; i += 8)
    tile[ty + i][tx] = in[(size_t)(r0 + ty + i) * si + (c0 + tx)];
  __syncthreads();
#pragma unroll
  for (int i = 0; i < 32; i += 8)
    out[(size_t)(c0 + ty + i) * so + (r0 + tx)] = __float2bfloat16(tile[tx][ty + i]);
}

// ---------------- RoPE fp32(stride si) -> bf16 (pos = row index) ----------------
__global__ void rope_cvt_kernel(const float* __restrict__ in, bf16* __restrict__ out,
                                int nheads, int hshift, int si) {
  int idx = blockIdx.x * blockDim.x + threadIdx.x;  // over SEQ*nheads*64
  int i = idx & 63;
  int h = (idx >> 6) & (nheads - 1);
  int s = idx >> (6 + hshift);
  if (s >= SEQ) return;
  float inv = __expf(-(float)i * 0.14391156831212787f);  // ln(10000)/64
  float ang = (float)s * inv;
  float sn, cs;
  __sincosf(ang, &sn, &cs);
  size_t bi = (size_t)s * si + (size_t)h * HD + i;
  size_t bo = (size_t)s * ((size_t)nheads * HD) + (size_t)h * HD + i;
  float x1 = in[bi], x2 = in[bi + 64];
  out[bo]      = __float2bfloat16(x1 * cs - x2 * sn);
  out[bo + 64] = __float2bfloat16(x2 * cs + x1 * sn);
}

// ---------------- GEMM: C[M][N] = A[M][K] * Bt[N][K]^T + bias ----------------
__global__ __launch_bounds__(256) void gemm_bt_kernel(
    const bf16* __restrict__ A, const bf16* __restrict__ Bt,
    const float* __restrict__ bias, float* __restrict__ C,
    int M, int N, int K) {
  __shared__ bf16 As[128 * 64];
  __shared__ bf16 Bs[128 * 64];
  const int tid = threadIdx.x;
  const int lane = tid & 63;
  const int w = tid >> 6;
  const int wm = w >> 1, wn = w & 1;
  const int m0 = blockIdx.y * 128;
  const int n0 = blockIdx.x * 128;

  f32x4 acc[4][4];
  const f32x4 z = {0.f, 0.f, 0.f, 0.f};
#pragma unroll
  for (int i = 0; i < 4; i++)
#pragma unroll
    for (int j = 0; j < 4; j++) acc[i][j] = z;

  for (int kk = 0; kk < K; kk += 64) {
#pragma unroll
    for (int it = 0; it < 4; ++it) {
      int c = w * 4 + it;
      int row = c * 8 + (lane >> 3);
      int sb = ((lane & 7) * 16) ^ ((row & 7) << 4);
      gl_lds16(A + (size_t)(m0 + row) * K + kk + (sb >> 1), &As[c * 512]);
      gl_lds16(Bt + (size_t)(n0 + row) * K + kk + (sb >> 1), &Bs[c * 512]);
    }
    __syncthreads();
#pragma unroll
    for (int ks = 0; ks < 64; ks += 32) {
      bf16x8 a[4], b[4];
#pragma unroll
      for (int mi = 0; mi < 4; ++mi) {
        int r = wm * 64 + mi * 16 + (lane & 15);
        int byt = r * 128 + (((ks + (lane >> 4) * 8) * 2) ^ ((r & 7) << 4));
        a[mi] = *reinterpret_cast<const bf16x8*>(reinterpret_cast<const char*>(As) + byt);
      }
#pragma unroll
      for (int ni = 0; ni < 4; ++ni) {
        int r = wn * 64 + ni * 16 + (lane & 15);
        int byt = r * 128 + (((ks + (lane >> 4) * 8) * 2) ^ ((r & 7) << 4));
        b[ni] = *reinterpret_cast<const bf16x8*>(reinterpret_cast<const char*>(Bs) + byt);
      }
#pragma unroll
      for (int mi = 0; mi < 4; ++mi)
#pragma unroll
        for (int ni = 0; ni < 4; ++ni)
          acc[mi][ni] = __builtin_amdgcn_mfma_f32_16x16x32_bf16(a[mi], b[ni], acc[mi][ni], 0, 0, 0);
    }
    __syncthreads();
  }
#pragma unroll
  for (int ni = 0; ni < 4; ++ni) {
    int col = n0 + wn * 64 + ni * 16 + (lane & 15);
    float bv = bias ? bias[col] : 0.0f;
#pragma unroll
    for (int mi = 0; mi < 4; ++mi) {
      int rbase = m0 + wm * 64 + mi * 16 + (lane >> 4) * 4;
#pragma unroll
      for (int r = 0; r < 4; ++r)
        C[(size_t)(rbase + r) * N + col] = acc[mi][ni][r] + bv;
    }
  }
}

// ---------------- flash attention with KV-split load balancing ----------------
__global__ __launch_bounds__(256) void attn_kernel(
    const bf16* __restrict__ Q,   // [SEQ][HID]
    const bf16* __restrict__ Kb,  // [SEQ][KVDIM]
    const bf16* __restrict__ Vt,  // [KVDIM][SEQ]  (row = kvh*128+d)
    bf16* __restrict__ AO,        // [SEQ][HID]
    float* __restrict__ Opart,    // [2][NH][1024][HD] fp32 un-normalized
    float* __restrict__ Ml) {     // [2][NH][1024][2]  (m, l)
  __shared__ bf16 Ks[64 * 128];   // [kv][d], swizzled
  __shared__ bf16 Vs[128 * 64];   // [d][kv], swizzled
  __shared__ bf16 Ps[4][16 * 64]; // per-wave [q][kv], swizzled
  const int tid = threadIdx.x, lane = tid & 63, w = tid >> 6;
  const int b = blockIdx.x;
  const int H = b & 31;
  const int tt = b >> 5;
  int qb, lo, hi, half;
  bool split;
  if (tt < 32) {
    qb = 16 + ((31 - tt) >> 1);
    half = tt & 1;
    int n = qb + 1, mid = n >> 1;
    lo = half ? mid : 0;
    hi = half ? n : mid;
    split = true;
  } else {
    qb = 47 - tt;
    half = 0;
    lo = 0;
    hi = qb + 1;
    split = false;
  }
  const int kvh = H >> 2;
  const int qw = qb * 64 + w * 16;

  bf16x8 aq[4];
#pragma unroll
  for (int kd = 0; kd < 4; ++kd) {
    int row = qw + (lane & 15);
    int d = kd * 32 + (lane >> 4) * 8;
    aq[kd] = *reinterpret_cast<const bf16x8*>(Q + (size_t)row * HID + H * HD + d);
  }

  float m_run[4], l_run[4];
  f32x4 o[8];
  const f32x4 z = {0.f, 0.f, 0.f, 0.f};
#pragma unroll
  for (int r = 0; r < 4; ++r) { m_run[r] = -1e30f; l_run[r] = 0.0f; }
#pragma unroll
  for (int dt = 0; dt < 8; ++dt) o[dt] = z;

  const float scale = 0.08838834764831845f;  // 1/sqrt(128)

  for (int t = lo; t < hi; ++t) {
    int kvbase = t * 64;
#pragma unroll
    for (int it = 0; it < 4; ++it) {
      int c = w * 4 + it;
      int row = c * 4 + (lane >> 4);
      int sb = ((lane & 15) * 16) ^ ((row & 7) << 4);
      gl_lds16(Kb + (size_t)(kvbase + row) * KVDIM + kvh * HD + (sb >> 1), &Ks[c * 512]);
    }
#pragma unroll
    for (int it = 0; it < 4; ++it) {
      int c = w * 4 + it;
      int row = c * 8 + (lane >> 3);
      int sb = ((lane & 7) * 16) ^ ((row & 7) << 4);
      gl_lds16(Vt + (size_t)(kvh * HD + row) * SEQ + kvbase + (sb >> 1), &Vs[c * 512]);
    }
    __syncthreads();

    f32x4 sf[4];
#pragma unroll
    for (int j = 0; j < 4; ++j) sf[j] = z;
#pragma unroll
    for (int j = 0; j < 4; ++j) {
#pragma unroll
      for (int kd = 0; kd < 4; ++kd) {
        int r = j * 16 + (lane & 15);
        int byt = r * 256 + (((kd * 32 + (lane >> 4) * 8) * 2) ^ ((r & 7) << 4));
        bf16x8 bfr = *reinterpret_cast<const bf16x8*>(reinterpret_cast<const char*>(Ks) + byt);
        sf[j] = __builtin_amdgcn_mfma_f32_16x16x32_bf16(aq[kd], bfr, sf[j], 0, 0, 0);
      }
    }

    float vals[4][4];
    bool diag = (t == qb);
#pragma unroll
    for (int j = 0; j < 4; ++j)
#pragma unroll
      for (int r = 0; r < 4; ++r) {
        float v = sf[j][r] * scale;
        if (diag) {
          int qa = qw + (lane >> 4) * 4 + r;
          int ka = kvbase + j * 16 + (lane & 15);
          if (ka > qa) v = -1e30f;
        }
        vals[j][r] = v;
      }

    float mt[4], alpha[4];
#pragma unroll
    for (int r = 0; r < 4; ++r) {
      float m = fmaxf(fmaxf(vals[0][r], vals[1][r]), fmaxf(vals[2][r], vals[3][r]));
#pragma unroll
      for (int sh = 8; sh >= 1; sh >>= 1) m = fmaxf(m, __shfl_xor(m, sh, 16));
      float mn = fmaxf(m_run[r], m);
      alpha[r] = __expf(m_run[r] - mn);
      m_run[r] = mn;
      mt[r] = mn;
    }

    float rs[4] = {0.f, 0.f, 0.f, 0.f};
#pragma unroll
    for (int j = 0; j < 4; ++j)
#pragma unroll
      for (int r = 0; r < 4; ++r) {
        float p = __expf(vals[j][r] - mt[r]);
        rs[r] += p;
        int prow = (lane >> 4) * 4 + r;
        int pcol = j * 16 + (lane & 15);
        int byt = prow * 128 + ((pcol * 2) ^ ((prow & 7) << 4));
        *reinterpret_cast<bf16*>(reinterpret_cast<char*>(&Ps[w][0]) + byt) = __float2bfloat16(p);
      }
#pragma unroll
    for (int r = 0; r < 4; ++r) {
#pragma unroll
      for (int sh = 8; sh >= 1; sh >>= 1) rs[r] += __shfl_xor(rs[r], sh, 16);
      l_run[r] = l_run[r] * alpha[r] + rs[r];
    }
#pragma unroll
    for (int dt = 0; dt < 8; ++dt)
#pragma unroll
      for (int r = 0; r < 4; ++r) o[dt][r] *= alpha[r];

    bf16x8 pa[2];
#pragma unroll
    for (int ks = 0; ks < 2; ++ks) {
      int prow = lane & 15;
      int byt = prow * 128 + (((ks * 32 + (lane >> 4) * 8) * 2) ^ ((prow & 7) << 4));
      pa[ks] = *reinterpret_cast<const bf16x8*>(reinterpret_cast<const char*>(&Ps[w][0]) + byt);
    }
#pragma unroll
    for (int dt = 0; dt < 8; ++dt)
#pragma unroll
      for (int ks = 0; ks < 2; ++ks) {
        int vrow = dt * 16 + (lane & 15);
        int byt = vrow * 128 + (((ks * 32 + (lane >> 4) * 8) * 2) ^ ((vrow & 7) << 4));
        bf16x8 vb = *reinterpret_cast<const bf16x8*>(reinterpret_cast<const char*>(Vs) + byt);
        o[dt] = __builtin_amdgcn_mfma_f32_16x16x32_bf16(pa[ks], vb, o[dt], 0, 0, 0);
      }
    __syncthreads();
  }

  if (!split) {
#pragma unroll
    for (int dt = 0; dt < 8; ++dt)
#pragma unroll
      for (int r = 0; r < 4; ++r) {
        int qa = qw + (lane >> 4) * 4 + r;
        int d = dt * 16 + (lane & 15);
        AO[(size_t)qa * HID + H * HD + d] = __float2bfloat16(o[dt][r] / l_run[r]);
      }
  } else {
    size_t pbase = ((size_t)(half * NH + H) * 1024);
#pragma unroll
    for (int dt = 0; dt < 8; ++dt)
#pragma unroll
      for (int r = 0; r < 4; ++r) {
        int qa = qw + (lane >> 4) * 4 + r;
        int d = dt * 16 + (lane & 15);
        Opart[(pbase + (qa - 1024)) * HD + d] = o[dt][r];
      }
    if ((lane & 15) == 0) {
#pragma unroll
      for (int r = 0; r < 4; ++r) {
        int qa = qw + (lane >> 4) * 4 + r;
        Ml[(pbase + (qa - 1024)) * 2 + 0] = m_run[r];
        Ml[(pbase + (qa - 1024)) * 2 + 1] = l_run[r];
      }
    }
  }
}

// ---------------- merge split-attention partials ----------------
__global__ __launch_bounds__(256) void merge_kernel(
    const float* __restrict__ Opart, const float* __restrict__ Ml,
    bf16* __restrict__ AO) {
  int i = blockIdx.x * 256 + threadIdx.x;  // over NH*1024*32 (float4 per thread)
  int dq = (i & 31) << 2;
  int row = (i >> 5) & 1023;
  int H = i >> 15;
  size_t b1 = (size_t)H * 1024 + row;
  size_t b2 = (size_t)(NH + H) * 1024 + row;
  float m1 = Ml[b1 * 2], l1 = Ml[b1 * 2 + 1];
  float m2 = Ml[b2 * 2], l2 = Ml[b2 * 2 + 1];
  float M = fmaxf(m1, m2);
  float w1 = __expf(m1 - M), w2 = __expf(m2 - M);
  float inv = 1.0f / (l1 * w1 + l2 * w2);
  float4 o1 = *reinterpret_cast<const float4*>(Opart + b1 * HD + dq);
  float4 o2 = *reinterpret_cast<const float4*>(Opart + b2 * HD + dq);
  bf16 o[4] = {__float2bfloat16((o1.x * w1 + o2.x * w2) * inv),
               __float2bfloat16((o1.y * w1 + o2.y * w2) * inv),
               __float2bfloat16((o1.z * w1 + o2.z * w2) * inv),
               __float2bfloat16((o1.w * w1 + o2.w * w2) * inv)};
  *reinterpret_cast<short4*>(AO + (size_t)(1024 + row) * HID + H * HD + dq) =
      *reinterpret_cast<const short4*>(o);
}

extern "C" void kernel_launch(void* const* d_in, const int* in_sizes, int n_in,
                              void* d_out, int out_size, void* d_ws, size_t ws_size,
                              hipStream_t stream) {
  const float* hidden = (const float*)d_in[0];
  const float* Wq = (const float*)d_in[2];
  const float* bq = (const float*)d_in[3];
  const float* Wk = (const float*)d_in[4];
  const float* bk = (const float*)d_in[5];
  const float* Wv = (const float*)d_in[6];
  const float* bv = (const float*)d_in[7];
  const float* Wo = (const float*)d_in[8];
  float* out = (float*)d_out;

  char* w = (char*)d_ws;
  bf16* Xb    = (bf16*)w; w += (size_t)SEQ * HID * 2;
  bf16* Wqkvt = (bf16*)w; w += (size_t)QKVN * HID * 2;   // rows: [Q 4096 | K 1024 | V 1024]
  bf16* Wot   = (bf16*)w; w += (size_t)HID * HID * 2;
  bf16* Qb    = (bf16*)w; w += (size_t)SEQ * HID * 2;
  bf16* Kb    = (bf16*)w; w += (size_t)SEQ * KVDIM * 2;
  bf16* Vt    = (bf16*)w; w += (size_t)KVDIM * SEQ * 2;
  float* bqkv = (float*)w; w += (size_t)QKVN * 4;
  float* Cqkv = (float*)w; w += (size_t)SEQ * QKVN * 4;  // [2048][6144] fused QKV out
  bf16* AO = (bf16*)Cqkv;           // alias: Cqkv dead after rope/V-transpose
  float* Opart = (float*)Wqkvt;     // alias: Wqkvt (50.3 MB) dead after QKV GEMM; Opart = 33.5 MB
  float* Ml = Opart + (size_t)2 * NH * 1024 * HD;  // FLOAT offset: +33.5 MB, size 0.5 MB -> fits

  cvt_kernel<<<(SEQ * HID) / 1024, 256, 0, stream>>>(hidden, Xb, SEQ * HID);
  concat_bias_kernel<<<QKVN / 256, 256, 0, stream>>>(bq, bk, bv, bqkv);
  transpose_cvt_kernel<<<dim3(HID / 32, HID / 32), dim3(32, 8), 0, stream>>>(
      Wq, Wqkvt, HID, HID);
  transpose_cvt_kernel<<<dim3(KVDIM / 32, HID / 32), dim3(32, 8), 0, stream>>>(
      Wk, Wqkvt + (size_t)HID * HID, KVDIM, HID);
  transpose_cvt_kernel<<<dim3(KVDIM / 32, HID / 32), dim3(32, 8), 0, stream>>>(
      Wv, Wqkvt + (size_t)(HID + KVDIM) * HID, KVDIM, HID);
  transpose_cvt_kernel<<<dim3(HID / 32, HID / 32), dim3(32, 8), 0, stream>>>(
      Wo, Wot, HID, HID);

  gemm_bt_kernel<<<dim3(QKVN / 128, SEQ / 128), 256, 0, stream>>>(
      Xb, Wqkvt, bqkv, Cqkv, SEQ, QKVN, HID);

  rope_cvt_kernel<<<(SEQ * NH * 64) / 256, 256, 0, stream>>>(Cqkv, Qb, NH, 5, QKVN);
  rope_cvt_kernel<<<(SEQ * NKV * 64) / 256, 256, 0, stream>>>(Cqkv + HID, Kb, NKV, 3, QKVN);
  transpose_cvt_kernel<<<dim3(KVDIM / 32, SEQ / 32), dim3(32, 8), 0, stream>>>(
      Cqkv + HID + KVDIM, Vt, QKVN, SEQ);

  attn_kernel<<<1536, 256, 0, stream>>>(Qb, Kb, Vt, AO, Opart, Ml);
  merge_kernel<<<(NH * 1024 * 32) / 256, 256, 0, stream>>>(Opart, Ml, AO);

  gemm_bt_kernel<<<dim3(HID / 128, SEQ / 128), 256, 0, stream>>>(
      AO, Wot, nullptr, out, SEQ, HID, HID);
}